// Round 6
// baseline (211.157 us; speedup 1.0000x reference)
//
#include <hip/hip_runtime.h>

// ---------------------------------------------------------------------------
// Compile-time Wigner 3j (exact port of the reference Python, fp64)
// ---------------------------------------------------------------------------
struct CD { double re, im; };
constexpr CD cmul(CD a, CD b){ return CD{a.re*b.re - a.im*b.im, a.re*b.im + a.im*b.re}; }
constexpr CD conj_(CD a){ return CD{a.re, -a.im}; }

constexpr double factd(int n){ double r = 1.0; for(int i = 2; i <= n; ++i) r *= (double)i; return r; }
constexpr double csqrt_(double x){
  if (x <= 0.0) return 0.0;
  double g = x > 1.0 ? x : 1.0;
  for (int i = 0; i < 100; ++i) g = 0.5*(g + x/g);
  return g;
}

constexpr double su2_cg(int j1,int m1,int j2,int m2,int j3,int m3){
  if (m3 != m1 + m2) return 0.0;
  int vmin = -j1 + j2 + m3;
  if (-j1 + m1 > vmin) vmin = -j1 + m1;
  if (0 > vmin) vmin = 0;
  int vmax = j2 + j3 + m1;
  if (j3 - j1 + j2 < vmax) vmax = j3 - j1 + j2;
  if (j3 + m3 < vmax) vmax = j3 + m3;
  double c = csqrt_((2.0*j3 + 1.0) * factd(j3 + j1 - j2) * factd(j3 - j1 + j2) * factd(j1 + j2 - j3)
                    * factd(j3 + m3) * factd(j3 - m3)
                    / (factd(j1 + j2 + j3 + 1) * factd(j1 - m1) * factd(j1 + m1)
                       * factd(j2 - m2) * factd(j2 + m2)));
  double s = 0.0;
  for (int v = vmin; v <= vmax; ++v){
    double t = (((v + j2 + m2) & 1) ? -1.0 : 1.0) / factd(v)
               * factd(j2 + j3 + m1 - v) * factd(j1 - m1 + v)
               / factd(j3 - j1 + j2 - v) / factd(j3 + m3 - v) / factd(v + j1 - j2 - m3);
    s += t;
  }
  return c * s;
}

struct QM { CD m[7][7]; };
constexpr QM qmat(int l){
  QM q{};
  double is2 = 1.0 / csqrt_(2.0);
  for (int mm = -l; mm < 0; ++mm){
    q.m[l+mm][l-mm] = CD{is2, 0.0};
    q.m[l+mm][l+mm] = CD{0.0, -is2};
  }
  q.m[l][l] = CD{1.0, 0.0};
  for (int mm = 1; mm <= l; ++mm){
    double sgn = (mm & 1) ? -1.0 : 1.0;
    q.m[l+mm][l+mm] = CD{sgn*is2, 0.0};
    q.m[l+mm][l-mm] = CD{0.0, sgn*is2};
  }
  CD ph = (l % 4 == 0) ? CD{1,0} : (l % 4 == 1) ? CD{0,-1} : (l % 4 == 2) ? CD{-1,0} : CD{0,1};
  for (int r = 0; r < 7; ++r)
    for (int c = 0; c < 7; ++c)
      q.m[r][c] = cmul(ph, q.m[r][c]);
  return q;
}

template<int L1,int L2,int L3> struct W3JT { float v[2*L1+1][2*L2+1][2*L3+1]; };

template<int L1,int L2,int L3>
constexpr W3JT<L1,L2,L3> make_w3j(){
  constexpr int D1 = 2*L1+1, D2 = 2*L2+1, D3 = 2*L3+1;
  QM q1 = qmat(L1), q2 = qmat(L2), q3 = qmat(L3);
  double cg[7][7] = {};
  for (int i = 0; i < D1; ++i)
    for (int k = 0; k < D2; ++k){
      int n = i + k - L1 - L2 + L3;
      if (n >= 0 && n < D3) cg[i][k] = su2_cg(L1, i-L1, L2, k-L2, L3, (i-L1)+(k-L2));
    }
  double c[D1][D2][D3] = {};
  double norm2 = 0.0;
  for (int j = 0; j < D1; ++j)
    for (int l = 0; l < D2; ++l)
      for (int m = 0; m < D3; ++m){
        CD s{0.0, 0.0};
        for (int i = 0; i < D1; ++i)
          for (int k = 0; k < D2; ++k){
            double g = cg[i][k];
            if (g == 0.0) continue;
            int n = i + k - L1 - L2 + L3;
            CD t = cmul(q1.m[i][j], q2.m[k][l]);
            t = cmul(t, conj_(q3.m[n][m]));
            s.re += t.re * g; s.im += t.im * g;
          }
        c[j][l][m] = s.re;
        norm2 += s.re * s.re;
      }
  double inv = 1.0 / csqrt_(norm2);
  W3JT<L1,L2,L3> w{};
  for (int j = 0; j < D1; ++j)
    for (int l = 0; l < D2; ++l)
      for (int m = 0; m < D3; ++m){
        double val = c[j][l][m] * inv;
        if (val < 1e-10 && val > -1e-10) val = 0.0;
        w.v[j][l][m] = (float)val;
      }
  return w;
}

// ---------------------------------------------------------------------------
// Path tables (lexicographic e3nn order)
// ---------------------------------------------------------------------------
__device__ __constant__ int L3P_[23]  = {0,1,2,3,1,0,2,1,3,2,2,1,3,0,2,1,3,3,2,1,3,0,2};
// swap = (D1 < D2): MFMA K-dim takes mul1 side, serial loop takes mul2 side
__device__ __constant__ int SWAPP_[23] = {0,1,1,1,0,0,0,1,1,1,0,0,0,0,0,1,1,0,0,0,0,0,0};
// cumulative K3 (2*l3+1) before each path; [23] = 99
constexpr int K3CUM[24] = {0,1,4,9,16,19,20,25,28,35,40,45,48,55,56,61,64,71,78,83,86,93,94,99};
constexpr size_t ZW = 2048ull * 64ull;   // elements per unit of K3

typedef __bf16 bf16x8 __attribute__((ext_vector_type(8)));
typedef float  f32x4  __attribute__((ext_vector_type(4)));

// ---------------------------------------------------------------------------
// Prep 1: pack weights fp32 -> bf16 (path coeff folded in), B-fragment order.
// idx = ((((p*64+s)*2+hf)*4+nt)*64+lane)*8 + e
// K-elem kv = hf*32 + (lane>>4)*8 + e ; col wc = nt*16 + (lane&15)
// no-swap: value = W[p][s][kv][wc] ; swap: value = W[p][kv][s][wc]
// ---------------------------------------------------------------------------
__global__ void pack_w_kernel(const float* __restrict__ w, unsigned short* __restrict__ wp, int total){
  int idx = blockIdx.x * 256 + threadIdx.x;
  if (idx >= total) return;
  int e    = idx & 7;
  int lane = (idx >> 3) & 63;
  int nt   = (idx >> 9) & 3;
  int hf   = (idx >> 11) & 1;
  int s    = (idx >> 12) & 63;
  int p    = idx >> 18;
  int kv = hf*32 + (lane >> 4)*8 + e;
  int wc = nt*16 + (lane & 15);
  int l3 = L3P_[p];
  const float nto[4] = {4.f, 6.f, 7.f, 6.f};
  float coeff = sqrtf((2.f*l3 + 1.f) / (nto[l3] * 4096.f));
  int a = SWAPP_[p] ? kv : s;
  int b = SWAPP_[p] ? s : kv;
  float val = w[(((size_t)p*64 + a)*64 + b)*64 + wc] * coeff;
  unsigned bits = __builtin_bit_cast(unsigned, val);
  unsigned r = (bits + 0x7FFFu + ((bits >> 16) & 1u)) >> 16;   // RNE
  wp[idx] = (unsigned short)r;
}

// ---------------------------------------------------------------------------
// Prep 2: transpose x [2048][1024] -> xT [1024][2048]
// ---------------------------------------------------------------------------
__global__ void transpose_x(const float* __restrict__ x, float* __restrict__ xT){
  __shared__ float t[32][33];
  int bx = blockIdx.x, by = blockIdx.y;
  int tx = threadIdx.x & 31, ty = threadIdx.x >> 5;
  #pragma unroll
  for (int r = 0; r < 4; ++r)
    t[ty + r*8][tx] = x[(size_t)(by*32 + ty + r*8)*1024 + bx*32 + tx];
  __syncthreads();
  #pragma unroll
  for (int r = 0; r < 4; ++r)
    xT[(size_t)(bx*32 + ty + r*8)*2048 + by*32 + tx] = t[tx][ty + r*8];
}

// ---------------------------------------------------------------------------
// Main slot: path P, k3 range [G0,G0+G). SWAP selects which mul feeds MFMA-K.
// 8 waves/block = 4 z-subtiles x 2 K-halves; 64 z per block.
// Waves on different z-subtiles read identical W fragments -> L1 reuse.
// Cross-wave (K-half) reduction per pair via 2-kk phases (2048 floats/pair).
// ---------------------------------------------------------------------------
template<int P,int L1,int L2,int L3,bool SWAP,int G0,int G,bool PART>
__device__ __forceinline__ void run_slot(
    int tile, const float* __restrict__ xT,
    const unsigned short* __restrict__ wp,
    float* __restrict__ dst, float* red)
{
  constexpr int K3 = 2*L3+1;
  constexpr int LK = SWAP ? L1 : L2;         // angular l of MFMA-K mul
  constexpr int LS = SWAP ? L2 : L1;         // angular l of serial mul
  constexpr int DK = 2*LK+1, DS = 2*LS+1;
  constexpr auto C = make_w3j<L1,L2,L3>();

  const int lane = threadIdx.x & 63;
  const int wid  = threadIdx.x >> 6;         // 0..7
  const int wv   = wid & 1;                  // K-half
  const int pr   = wid >> 1;                 // z-subtile 0..3
  const int zc   = tile*64 + pr*16 + (lane & 15);   // A row (z)
  float* redp = red + pr*2048;

  // held fragment: 8 K-mul indices x DK angular (coalesced via xT)
  float xk[8][DK];
  {
    const float* xkb = xT + (size_t)(64*LK*LK)*2048 + zc;
    const int t0 = wv*32 + (lane >> 4)*8;
    #pragma unroll
    for (int e = 0; e < 8; ++e)
      #pragma unroll
      for (int t = 0; t < DK; ++t)
        xk[e][t] = xkb[(size_t)((t0 + e)*DK + t)*2048];
  }

  const float* xsb = xT + (size_t)(64*LS*LS)*2048 + zc;
  const unsigned short* wu = wp + (size_t)P*262144 + (size_t)wv*2048 + (size_t)lane*8;

  f32x4 acc[G][4];
  #pragma unroll
  for (int a = 0; a < G; ++a)
    #pragma unroll
    for (int b = 0; b < 4; ++b) acc[a][b] = f32x4{0.f,0.f,0.f,0.f};

  // software-prefetched serial-x
  const float* xsp = xsb;
  float xs[DS];
  #pragma unroll
  for (int j = 0; j < DS; ++j) xs[j] = xsp[(size_t)j*2048];

  for (int s = 0; s < 64; ++s){
    bf16x8 bfrag[4];
    #pragma unroll
    for (int nt = 0; nt < 4; ++nt)
      bfrag[nt] = *reinterpret_cast<const bf16x8*>(wu + nt*512);

    const float* xnp = (s < 63) ? xsp + (size_t)DS*2048 : xsp;
    float xn[DS];
    #pragma unroll
    for (int j = 0; j < DS; ++j) xn[j] = xnp[(size_t)j*2048];

    #pragma unroll
    for (int kk = 0; kk < G; ++kk){
      float dk[DK];
      #pragma unroll
      for (int t = 0; t < DK; ++t) dk[t] = 0.f;
      #pragma unroll
      for (int t = 0; t < DK; ++t){
        #pragma unroll
        for (int j = 0; j < DS; ++j){
          const float cv = SWAP ? C.v[t][j][G0+kk] : C.v[j][t][G0+kk];
          if (cv != 0.0f) dk[t] = __builtin_fmaf(xs[j], cv, dk[t]);
        }
      }
      bf16x8 af;
      #pragma unroll
      for (int e = 0; e < 8; ++e){
        float t2 = 0.f;
        #pragma unroll
        for (int t = 0; t < DK; ++t) t2 = __builtin_fmaf(xk[e][t], dk[t], t2);
        af[e] = (__bf16)t2;
      }
      __builtin_amdgcn_s_setprio(1);
      #pragma unroll
      for (int nt = 0; nt < 4; ++nt)
        acc[kk][nt] = __builtin_amdgcn_mfma_f32_16x16x32_bf16(af, bfrag[nt], acc[kk][nt], 0, 0, 0);
      __builtin_amdgcn_s_setprio(0);
    }
    #pragma unroll
    for (int j = 0; j < DS; ++j) xs[j] = xn[j];
    xsp += (size_t)DS*2048;
    wu  += 4096;
  }

  // phased cross-wave (K-half) reduction: 2 kks per phase, roles alternate.
  auto store_one = [&](int kk, int nt, const f32x4& o, const f32x4& a){
    #pragma unroll
    for (int r = 0; r < 4; ++r){
      int zl = ((lane >> 4) << 2) + r;
      int wc = nt*16 + (lane & 15);
      float val = a[r] + o[r];
      if constexpr (PART){
        dst[(size_t)K3CUM[P]*ZW + (size_t)(tile*64 + pr*16 + zl)*(64*K3) + wc*K3 + (G0+kk)] = val;
      } else {
        unsafeAtomicAdd(dst + (size_t)(tile*64 + pr*16 + zl)*1024 + 64*L3*L3 + wc*K3 + (G0+kk), val);
      }
    }
  };

  constexpr int NPH = (G + 1) / 2;
  #pragma unroll
  for (int ph = 0; ph < NPH; ++ph){
    const int base = 2*ph;
    const int cnt  = (G - base) < 2 ? (G - base) : 2;
    const int writer = ph & 1;
    if (wv == writer){
      for (int q = 0; q < cnt; ++q)
        #pragma unroll
        for (int nt = 0; nt < 4; ++nt)
          *reinterpret_cast<f32x4*>(&redp[((q*4 + nt)*64 + lane)*4]) = acc[base+q][nt];
    }
    __syncthreads();
    if (wv != writer){
      for (int q = 0; q < cnt; ++q)
        #pragma unroll
        for (int nt = 0; nt < 4; ++nt){
          f32x4 o = *reinterpret_cast<const f32x4*>(&redp[((q*4 + nt)*64 + lane)*4]);
          store_one(base+q, nt, o, acc[base+q][nt]);
        }
    }
    if (ph + 1 < NPH) __syncthreads();
  }
}

template<bool PART>
__global__ __launch_bounds__(512, 2) void tp_main(const float* __restrict__ xT,
    const unsigned short* __restrict__ wp, float* __restrict__ dst)
{
  __shared__ __align__(16) float red[8192];   // 32 KB: 4 pairs x 2048 floats
  const int slot = blockIdx.x >> 5;
  const int tile = blockIdx.x & 31;
  switch (slot){
    // 36 slots, heavy-first; every branch sized to avoid spills.
    case 0:  run_slot< 6,1,1,2,false,0,5,PART>(tile,xT,wp,dst,red); break;
    case 1:  run_slot<16,2,3,3,true ,0,3,PART>(tile,xT,wp,dst,red); break;
    case 2:  run_slot<20,3,2,3,false,0,3,PART>(tile,xT,wp,dst,red); break;
    case 3:  run_slot<14,2,2,2,false,0,3,PART>(tile,xT,wp,dst,red); break;
    case 4:  run_slot<15,2,3,1,true ,0,3,PART>(tile,xT,wp,dst,red); break;
    case 5:  run_slot<19,3,2,1,false,0,3,PART>(tile,xT,wp,dst,red); break;
    case 6:  run_slot< 8,1,2,3,true ,0,4,PART>(tile,xT,wp,dst,red); break;
    case 7:  run_slot<12,2,1,3,false,0,4,PART>(tile,xT,wp,dst,red); break;
    case 8:  run_slot<22,3,3,2,false,0,2,PART>(tile,xT,wp,dst,red); break;
    case 9:  run_slot<22,3,3,2,false,2,2,PART>(tile,xT,wp,dst,red); break;
    case 10: run_slot< 9,1,3,2,true ,0,3,PART>(tile,xT,wp,dst,red); break;
    case 11: run_slot<16,2,3,3,true ,3,2,PART>(tile,xT,wp,dst,red); break;
    case 12: run_slot<16,2,3,3,true ,5,2,PART>(tile,xT,wp,dst,red); break;
    case 13: run_slot<20,3,2,3,false,3,2,PART>(tile,xT,wp,dst,red); break;
    case 14: run_slot<20,3,2,3,false,5,2,PART>(tile,xT,wp,dst,red); break;
    case 15: run_slot< 2,0,2,2,true ,0,5,PART>(tile,xT,wp,dst,red); break;
    case 16: run_slot<10,2,0,2,false,0,5,PART>(tile,xT,wp,dst,red); break;
    case 17: run_slot<11,2,1,1,false,0,3,PART>(tile,xT,wp,dst,red); break;
    case 18: run_slot< 7,1,2,1,true ,0,3,PART>(tile,xT,wp,dst,red); break;
    case 19: run_slot<18,3,1,2,false,0,3,PART>(tile,xT,wp,dst,red); break;
    case 20: run_slot< 8,1,2,3,true ,4,3,PART>(tile,xT,wp,dst,red); break;
    case 21: run_slot<12,2,1,3,false,4,3,PART>(tile,xT,wp,dst,red); break;
    case 22: run_slot<14,2,2,2,false,3,2,PART>(tile,xT,wp,dst,red); break;
    case 23: run_slot< 9,1,3,2,true ,3,2,PART>(tile,xT,wp,dst,red); break;
    case 24: run_slot<18,3,1,2,false,3,2,PART>(tile,xT,wp,dst,red); break;
    case 25: run_slot<22,3,3,2,false,4,1,PART>(tile,xT,wp,dst,red); break;
    case 26: run_slot<21,3,3,0,false,0,1,PART>(tile,xT,wp,dst,red); break;
    case 27: run_slot< 3,0,3,3,true ,0,4,PART>(tile,xT,wp,dst,red); break;
    case 28: run_slot<17,3,0,3,false,0,4,PART>(tile,xT,wp,dst,red); break;
    case 29: run_slot< 3,0,3,3,true ,4,3,PART>(tile,xT,wp,dst,red); break;
    case 30: run_slot<17,3,0,3,false,4,3,PART>(tile,xT,wp,dst,red); break;
    case 31: run_slot< 1,0,1,1,true ,0,3,PART>(tile,xT,wp,dst,red); break;
    case 32: run_slot< 4,1,0,1,false,0,3,PART>(tile,xT,wp,dst,red); break;
    case 33: run_slot<13,2,2,0,false,0,1,PART>(tile,xT,wp,dst,red); break;
    case 34: run_slot< 5,1,1,0,false,0,1,PART>(tile,xT,wp,dst,red); break;
    case 35: run_slot< 0,0,0,0,false,0,1,PART>(tile,xT,wp,dst,red); break;
    default: break;
  }
}

// ---------------------------------------------------------------------------
// Gather: out[z][seg] = sum of per-path partials (coeff already folded in)
// ---------------------------------------------------------------------------
__global__ void gather_out(const float* __restrict__ part, float* __restrict__ out){
  int gid = blockIdx.x * 256 + threadIdx.x;
  int z = gid >> 10, j = gid & 1023;
  float s;
  if (j < 64){                               // l3=0: paths {0,5,13,21}
    size_t b = (size_t)z*64 + j;
    s = part[(size_t)K3CUM[0]*ZW + b] + part[(size_t)K3CUM[5]*ZW + b]
      + part[(size_t)K3CUM[13]*ZW + b] + part[(size_t)K3CUM[21]*ZW + b];
  } else if (j < 256){                       // l3=1: paths {1,4,7,11,15,19}
    size_t b = (size_t)z*192 + (j - 64);
    s = part[(size_t)K3CUM[1]*ZW + b] + part[(size_t)K3CUM[4]*ZW + b]
      + part[(size_t)K3CUM[7]*ZW + b] + part[(size_t)K3CUM[11]*ZW + b]
      + part[(size_t)K3CUM[15]*ZW + b] + part[(size_t)K3CUM[19]*ZW + b];
  } else if (j < 576){                       // l3=2: paths {2,6,9,10,14,18,22}
    size_t b = (size_t)z*320 + (j - 256);
    s = part[(size_t)K3CUM[2]*ZW + b] + part[(size_t)K3CUM[6]*ZW + b]
      + part[(size_t)K3CUM[9]*ZW + b] + part[(size_t)K3CUM[10]*ZW + b]
      + part[(size_t)K3CUM[14]*ZW + b] + part[(size_t)K3CUM[18]*ZW + b]
      + part[(size_t)K3CUM[22]*ZW + b];
  } else {                                   // l3=3: paths {3,8,12,16,17,20}
    size_t b = (size_t)z*448 + (j - 576);
    s = part[(size_t)K3CUM[3]*ZW + b] + part[(size_t)K3CUM[8]*ZW + b]
      + part[(size_t)K3CUM[12]*ZW + b] + part[(size_t)K3CUM[16]*ZW + b]
      + part[(size_t)K3CUM[17]*ZW + b] + part[(size_t)K3CUM[20]*ZW + b];
  }
  out[gid] = s;
}

// ---------------------------------------------------------------------------
extern "C" void kernel_launch(void* const* d_in, const int* in_sizes, int n_in,
                              void* d_out, int out_size, void* d_ws, size_t ws_size,
                              hipStream_t stream)
{
  const float* x = (const float*)d_in[0];        // [2,1024,1024] fp32
  const float* w = (const float*)d_in[1];        // [23,64,64,64] fp32
  float* out = (float*)d_out;                    // [2,1024,1024] fp32

  const size_t packB = 23ull*64*2*4*64*8 * sizeof(unsigned short);   // 12,058,624
  const size_t xTB   = 1024ull*2048*sizeof(float);                   //  8,388,608
  const size_t partB = 99ull*ZW*sizeof(float);                       // 51,904,512
  const int totalW = 23*64*2*4*64*8;

  unsigned short* wp = (unsigned short*)d_ws;
  float* xT   = (float*)((char*)d_ws + packB);
  float* part = (float*)((char*)d_ws + packB + xTB);

  if (ws_size < packB + xTB) return;

  pack_w_kernel<<<(totalW + 255)/256, 256, 0, stream>>>(w, wp, totalW);
  dim3 tg(32, 64);
  transpose_x<<<tg, 256, 0, stream>>>(x, xT);

  if (ws_size >= packB + xTB + partB){
    tp_main<true><<<36*32, 512, 0, stream>>>(xT, wp, part);
    gather_out<<<(2048*1024)/256, 256, 0, stream>>>(part, out);
  } else {
    hipMemsetAsync(d_out, 0, (size_t)out_size * sizeof(float), stream);
    tp_main<false><<<36*32, 512, 0, stream>>>(xT, wp, out);
  }
}

// Round 7
// 203.473 us; speedup vs baseline: 1.0378x; 1.0378x over previous
//
#include <hip/hip_runtime.h>

// ---------------------------------------------------------------------------
// Compile-time Wigner 3j (exact port of the reference Python, fp64)
// ---------------------------------------------------------------------------
struct CD { double re, im; };
constexpr CD cmul(CD a, CD b){ return CD{a.re*b.re - a.im*b.im, a.re*b.im + a.im*b.re}; }
constexpr CD conj_(CD a){ return CD{a.re, -a.im}; }

constexpr double factd(int n){ double r = 1.0; for(int i = 2; i <= n; ++i) r *= (double)i; return r; }
constexpr double csqrt_(double x){
  if (x <= 0.0) return 0.0;
  double g = x > 1.0 ? x : 1.0;
  for (int i = 0; i < 100; ++i) g = 0.5*(g + x/g);
  return g;
}

constexpr double su2_cg(int j1,int m1,int j2,int m2,int j3,int m3){
  if (m3 != m1 + m2) return 0.0;
  int vmin = -j1 + j2 + m3;
  if (-j1 + m1 > vmin) vmin = -j1 + m1;
  if (0 > vmin) vmin = 0;
  int vmax = j2 + j3 + m1;
  if (j3 - j1 + j2 < vmax) vmax = j3 - j1 + j2;
  if (j3 + m3 < vmax) vmax = j3 + m3;
  double c = csqrt_((2.0*j3 + 1.0) * factd(j3 + j1 - j2) * factd(j3 - j1 + j2) * factd(j1 + j2 - j3)
                    * factd(j3 + m3) * factd(j3 - m3)
                    / (factd(j1 + j2 + j3 + 1) * factd(j1 - m1) * factd(j1 + m1)
                       * factd(j2 - m2) * factd(j2 + m2)));
  double s = 0.0;
  for (int v = vmin; v <= vmax; ++v){
    double t = (((v + j2 + m2) & 1) ? -1.0 : 1.0) / factd(v)
               * factd(j2 + j3 + m1 - v) * factd(j1 - m1 + v)
               / factd(j3 - j1 + j2 - v) / factd(j3 + m3 - v) / factd(v + j1 - j2 - m3);
    s += t;
  }
  return c * s;
}

struct QM { CD m[7][7]; };
constexpr QM qmat(int l){
  QM q{};
  double is2 = 1.0 / csqrt_(2.0);
  for (int mm = -l; mm < 0; ++mm){
    q.m[l+mm][l-mm] = CD{is2, 0.0};
    q.m[l+mm][l+mm] = CD{0.0, -is2};
  }
  q.m[l][l] = CD{1.0, 0.0};
  for (int mm = 1; mm <= l; ++mm){
    double sgn = (mm & 1) ? -1.0 : 1.0;
    q.m[l+mm][l+mm] = CD{sgn*is2, 0.0};
    q.m[l+mm][l-mm] = CD{0.0, sgn*is2};
  }
  CD ph = (l % 4 == 0) ? CD{1,0} : (l % 4 == 1) ? CD{0,-1} : (l % 4 == 2) ? CD{-1,0} : CD{0,1};
  for (int r = 0; r < 7; ++r)
    for (int c = 0; c < 7; ++c)
      q.m[r][c] = cmul(ph, q.m[r][c]);
  return q;
}

template<int L1,int L2,int L3> struct W3JT { float v[2*L1+1][2*L2+1][2*L3+1]; };

template<int L1,int L2,int L3>
constexpr W3JT<L1,L2,L3> make_w3j(){
  constexpr int D1 = 2*L1+1, D2 = 2*L2+1, D3 = 2*L3+1;
  QM q1 = qmat(L1), q2 = qmat(L2), q3 = qmat(L3);
  double cg[7][7] = {};
  for (int i = 0; i < D1; ++i)
    for (int k = 0; k < D2; ++k){
      int n = i + k - L1 - L2 + L3;
      if (n >= 0 && n < D3) cg[i][k] = su2_cg(L1, i-L1, L2, k-L2, L3, (i-L1)+(k-L2));
    }
  double c[D1][D2][D3] = {};
  double norm2 = 0.0;
  for (int j = 0; j < D1; ++j)
    for (int l = 0; l < D2; ++l)
      for (int m = 0; m < D3; ++m){
        CD s{0.0, 0.0};
        for (int i = 0; i < D1; ++i)
          for (int k = 0; k < D2; ++k){
            double g = cg[i][k];
            if (g == 0.0) continue;
            int n = i + k - L1 - L2 + L3;
            CD t = cmul(q1.m[i][j], q2.m[k][l]);
            t = cmul(t, conj_(q3.m[n][m]));
            s.re += t.re * g; s.im += t.im * g;
          }
        c[j][l][m] = s.re;
        norm2 += s.re * s.re;
      }
  double inv = 1.0 / csqrt_(norm2);
  W3JT<L1,L2,L3> w{};
  for (int j = 0; j < D1; ++j)
    for (int l = 0; l < D2; ++l)
      for (int m = 0; m < D3; ++m){
        double val = c[j][l][m] * inv;
        if (val < 1e-10 && val > -1e-10) val = 0.0;
        w.v[j][l][m] = (float)val;
      }
  return w;
}

// ---------------------------------------------------------------------------
// Path tables (lexicographic e3nn order)
// ---------------------------------------------------------------------------
__device__ __constant__ int L3P_[23]  = {0,1,2,3,1,0,2,1,3,2,2,1,3,0,2,1,3,3,2,1,3,0,2};
// swap = (D1 < D2): MFMA K-dim takes mul1 side, serial loop takes mul2 side
__device__ __constant__ int SWAPP_[23] = {0,1,1,1,0,0,0,1,1,1,0,0,0,0,0,1,1,0,0,0,0,0,0};
// cumulative K3 (2*l3+1) before each path; [23] = 99
constexpr int K3CUM[24] = {0,1,4,9,16,19,20,25,28,35,40,45,48,55,56,61,64,71,78,83,86,93,94,99};
constexpr size_t ZW = 2048ull * 64ull;   // elements per unit of K3

typedef __bf16 bf16x8 __attribute__((ext_vector_type(8)));
typedef float  f32x4  __attribute__((ext_vector_type(4)));
typedef float  f32x2  __attribute__((ext_vector_type(2)));

// ---------------------------------------------------------------------------
// Prep 1: pack weights fp32 -> bf16 (path coeff folded in), B-fragment order.
// idx = ((((p*64+s)*2+hf)*4+nt)*64+lane)*8 + e
// K-elem kv = hf*32 + (lane>>4)*8 + e ; col wc = nt*16 + (lane&15)
// no-swap: value = W[p][s][kv][wc] ; swap: value = W[p][kv][s][wc]
// ---------------------------------------------------------------------------
__global__ void pack_w_kernel(const float* __restrict__ w, unsigned short* __restrict__ wp, int total){
  int idx = blockIdx.x * 256 + threadIdx.x;
  if (idx >= total) return;
  int e    = idx & 7;
  int lane = (idx >> 3) & 63;
  int nt   = (idx >> 9) & 3;
  int hf   = (idx >> 11) & 1;
  int s    = (idx >> 12) & 63;
  int p    = idx >> 18;
  int kv = hf*32 + (lane >> 4)*8 + e;
  int wc = nt*16 + (lane & 15);
  int l3 = L3P_[p];
  const float nto[4] = {4.f, 6.f, 7.f, 6.f};
  float coeff = sqrtf((2.f*l3 + 1.f) / (nto[l3] * 4096.f));
  int a = SWAPP_[p] ? kv : s;
  int b = SWAPP_[p] ? s : kv;
  float val = w[(((size_t)p*64 + a)*64 + b)*64 + wc] * coeff;
  unsigned bits = __builtin_bit_cast(unsigned, val);
  unsigned r = (bits + 0x7FFFu + ((bits >> 16) & 1u)) >> 16;   // RNE
  wp[idx] = (unsigned short)r;
}

// ---------------------------------------------------------------------------
// Prep 2: transpose x [2048][1024] -> xT [1024][2048]
// ---------------------------------------------------------------------------
__global__ void transpose_x(const float* __restrict__ x, float* __restrict__ xT){
  __shared__ float t[32][33];
  int bx = blockIdx.x, by = blockIdx.y;
  int tx = threadIdx.x & 31, ty = threadIdx.x >> 5;
  #pragma unroll
  for (int r = 0; r < 4; ++r)
    t[ty + r*8][tx] = x[(size_t)(by*32 + ty + r*8)*1024 + bx*32 + tx];
  __syncthreads();
  #pragma unroll
  for (int r = 0; r < 4; ++r)
    xT[(size_t)(bx*32 + ty + r*8)*2048 + by*32 + tx] = t[tx][ty + r*8];
}

// ---------------------------------------------------------------------------
// Main slot: path P, k3 range [G0,G0+G). SWAP selects which mul feeds MFMA-K.
// 2 waves = K-halves; serial loop over the other mul (64 steps).
// af accumulation paired into f32x2 -> v_pk_fma_f32 (halves the issue count).
// red must hold Gh*4*64*4 floats; Gh<=3 -> 3072 floats (12 KB).
// ---------------------------------------------------------------------------
template<int P,int L1,int L2,int L3,bool SWAP,int G0,int G,bool PART>
__device__ __forceinline__ void run_slot(
    int tile, const float* __restrict__ xT,
    const unsigned short* __restrict__ wp,
    float* __restrict__ dst, float* red)
{
  constexpr int K3 = 2*L3+1;
  constexpr int LK = SWAP ? L1 : L2;         // angular l of MFMA-K mul
  constexpr int LS = SWAP ? L2 : L1;         // angular l of serial mul
  constexpr int DK = 2*LK+1, DS = 2*LS+1;
  constexpr auto C = make_w3j<L1,L2,L3>();

  const int lane = threadIdx.x & 63;
  const int wv   = threadIdx.x >> 6;         // K-half
  const int zc   = tile*16 + (lane & 15);    // A row (z)

  // held fragment: 4 e-pairs x DK angular, packed f32x2 (pairs of adjacent e)
  f32x2 xk2[4][DK];
  {
    const float* xkb = xT + (size_t)(64*LK*LK)*2048 + zc;
    const int t0 = wv*32 + (lane >> 4)*8;
    #pragma unroll
    for (int q = 0; q < 4; ++q)
      #pragma unroll
      for (int t = 0; t < DK; ++t){
        float lo = xkb[(size_t)((t0 + 2*q    )*DK + t)*2048];
        float hi = xkb[(size_t)((t0 + 2*q + 1)*DK + t)*2048];
        xk2[q][t] = f32x2{lo, hi};
      }
  }

  const float* xsb = xT + (size_t)(64*LS*LS)*2048 + zc;
  const unsigned short* wu = wp + (size_t)P*262144 + (size_t)wv*2048 + (size_t)lane*8;

  f32x4 acc[G][4];
  #pragma unroll
  for (int a = 0; a < G; ++a)
    #pragma unroll
    for (int b = 0; b < 4; ++b) acc[a][b] = f32x4{0.f,0.f,0.f,0.f};

  // software-prefetched serial-x
  const float* xsp = xsb;
  float xs[DS];
  #pragma unroll
  for (int j = 0; j < DS; ++j) xs[j] = xsp[(size_t)j*2048];

  for (int s = 0; s < 64; ++s){
    bf16x8 bfrag[4];
    #pragma unroll
    for (int nt = 0; nt < 4; ++nt)
      bfrag[nt] = *reinterpret_cast<const bf16x8*>(wu + nt*512);

    const float* xnp = (s < 63) ? xsp + (size_t)DS*2048 : xsp;
    float xn[DS];
    #pragma unroll
    for (int j = 0; j < DS; ++j) xn[j] = xnp[(size_t)j*2048];

    #pragma unroll
    for (int kk = 0; kk < G; ++kk){
      float dk[DK];
      #pragma unroll
      for (int t = 0; t < DK; ++t) dk[t] = 0.f;
      #pragma unroll
      for (int t = 0; t < DK; ++t){
        #pragma unroll
        for (int j = 0; j < DS; ++j){
          const float cv = SWAP ? C.v[t][j][G0+kk] : C.v[j][t][G0+kk];
          if (cv != 0.0f) dk[t] = __builtin_fmaf(xs[j], cv, dk[t]);
        }
      }
      // af via packed f32x2 FMA: 4 pk_fma per t instead of 8 scalar FMA
      f32x2 af2[4];
      #pragma unroll
      for (int q = 0; q < 4; ++q) af2[q] = f32x2{0.f, 0.f};
      #pragma unroll
      for (int t = 0; t < DK; ++t){
        const f32x2 d2 = f32x2{dk[t], dk[t]};
        #pragma unroll
        for (int q = 0; q < 4; ++q)
          af2[q] += xk2[q][t] * d2;          // -> v_pk_fma_f32
      }
      bf16x8 af;
      #pragma unroll
      for (int q = 0; q < 4; ++q){
        af[2*q]   = (__bf16)af2[q].x;
        af[2*q+1] = (__bf16)af2[q].y;
      }
      __builtin_amdgcn_s_setprio(1);
      #pragma unroll
      for (int nt = 0; nt < 4; ++nt)
        acc[kk][nt] = __builtin_amdgcn_mfma_f32_16x16x32_bf16(af, bfrag[nt], acc[kk][nt], 0, 0, 0);
      __builtin_amdgcn_s_setprio(0);
    }
    #pragma unroll
    for (int j = 0; j < DS; ++j) xs[j] = xn[j];
    xsp += (size_t)DS*2048;
    wu  += 4096;
  }

  // two-phase cross-wave reduction (12 KB LDS), both waves store half the kks
  constexpr int Gh = (G + 1) / 2;
  static_assert(Gh <= 3, "red[] sized for Gh<=3");
  auto store_one = [&](int kk, int nt, const f32x4& o, const f32x4& a){
    #pragma unroll
    for (int r = 0; r < 4; ++r){
      int zl = ((lane >> 4) << 2) + r;
      int wc = nt*16 + (lane & 15);
      float val = a[r] + o[r];
      if constexpr (PART){
        dst[(size_t)K3CUM[P]*ZW + (size_t)(tile*16 + zl)*(64*K3) + wc*K3 + (G0+kk)] = val;
      } else {
        unsafeAtomicAdd(dst + (size_t)(tile*16 + zl)*1024 + 64*L3*L3 + wc*K3 + (G0+kk), val);
      }
    }
  };

  if (wv == 1){
    #pragma unroll
    for (int kk = 0; kk < Gh; ++kk)
      #pragma unroll
      for (int nt = 0; nt < 4; ++nt)
        *reinterpret_cast<f32x4*>(&red[((kk*4 + nt)*64 + lane)*4]) = acc[kk][nt];
  }
  __syncthreads();
  if (wv == 0){
    #pragma unroll
    for (int kk = 0; kk < Gh; ++kk)
      #pragma unroll
      for (int nt = 0; nt < 4; ++nt){
        f32x4 o = *reinterpret_cast<const f32x4*>(&red[((kk*4 + nt)*64 + lane)*4]);
        store_one(kk, nt, o, acc[kk][nt]);
      }
  }
  if constexpr (G > Gh){
    if (wv == 0){
      #pragma unroll
      for (int kk = Gh; kk < G; ++kk)
        #pragma unroll
        for (int nt = 0; nt < 4; ++nt)
          *reinterpret_cast<f32x4*>(&red[(((kk-Gh)*4 + nt)*64 + lane)*4]) = acc[kk][nt];
    }
    __syncthreads();
    if (wv == 1){
      #pragma unroll
      for (int kk = Gh; kk < G; ++kk)
        #pragma unroll
        for (int nt = 0; nt < 4; ++nt){
          f32x4 o = *reinterpret_cast<const f32x4*>(&red[(((kk-Gh)*4 + nt)*64 + lane)*4]);
          store_one(kk, nt, o, acc[kk][nt]);
        }
    }
  }
}

template<bool PART>
__global__ __launch_bounds__(128, 3) void tp_main(const float* __restrict__ xT,
    const unsigned short* __restrict__ wp, float* __restrict__ dst)
{
  __shared__ __align__(16) float red[3072];   // 12 KB: Gh<=3 phases fit
  const int slot = blockIdx.x >> 7;
  const int tile = blockIdx.x & 127;
  switch (slot){
    // 36 slots, heavy-first; every branch sized for no spills under (128,3).
    case 0:  run_slot< 6,1,1,2,false,0,5,PART>(tile,xT,wp,dst,red); break;
    case 1:  run_slot<16,2,3,3,true ,0,3,PART>(tile,xT,wp,dst,red); break;
    case 2:  run_slot<20,3,2,3,false,0,3,PART>(tile,xT,wp,dst,red); break;
    case 3:  run_slot<14,2,2,2,false,0,3,PART>(tile,xT,wp,dst,red); break;
    case 4:  run_slot<15,2,3,1,true ,0,3,PART>(tile,xT,wp,dst,red); break;
    case 5:  run_slot<19,3,2,1,false,0,3,PART>(tile,xT,wp,dst,red); break;
    case 6:  run_slot< 8,1,2,3,true ,0,4,PART>(tile,xT,wp,dst,red); break;
    case 7:  run_slot<12,2,1,3,false,0,4,PART>(tile,xT,wp,dst,red); break;
    case 8:  run_slot<22,3,3,2,false,0,2,PART>(tile,xT,wp,dst,red); break;
    case 9:  run_slot<22,3,3,2,false,2,2,PART>(tile,xT,wp,dst,red); break;
    case 10: run_slot< 9,1,3,2,true ,0,3,PART>(tile,xT,wp,dst,red); break;
    case 11: run_slot<16,2,3,3,true ,3,2,PART>(tile,xT,wp,dst,red); break;
    case 12: run_slot<16,2,3,3,true ,5,2,PART>(tile,xT,wp,dst,red); break;
    case 13: run_slot<20,3,2,3,false,3,2,PART>(tile,xT,wp,dst,red); break;
    case 14: run_slot<20,3,2,3,false,5,2,PART>(tile,xT,wp,dst,red); break;
    case 15: run_slot< 2,0,2,2,true ,0,5,PART>(tile,xT,wp,dst,red); break;
    case 16: run_slot<10,2,0,2,false,0,5,PART>(tile,xT,wp,dst,red); break;
    case 17: run_slot<11,2,1,1,false,0,3,PART>(tile,xT,wp,dst,red); break;
    case 18: run_slot< 7,1,2,1,true ,0,3,PART>(tile,xT,wp,dst,red); break;
    case 19: run_slot<18,3,1,2,false,0,3,PART>(tile,xT,wp,dst,red); break;
    case 20: run_slot< 8,1,2,3,true ,4,3,PART>(tile,xT,wp,dst,red); break;
    case 21: run_slot<12,2,1,3,false,4,3,PART>(tile,xT,wp,dst,red); break;
    case 22: run_slot<14,2,2,2,false,3,2,PART>(tile,xT,wp,dst,red); break;
    case 23: run_slot< 9,1,3,2,true ,3,2,PART>(tile,xT,wp,dst,red); break;
    case 24: run_slot<18,3,1,2,false,3,2,PART>(tile,xT,wp,dst,red); break;
    case 25: run_slot<22,3,3,2,false,4,1,PART>(tile,xT,wp,dst,red); break;
    case 26: run_slot<21,3,3,0,false,0,1,PART>(tile,xT,wp,dst,red); break;
    case 27: run_slot< 3,0,3,3,true ,0,4,PART>(tile,xT,wp,dst,red); break;
    case 28: run_slot<17,3,0,3,false,0,4,PART>(tile,xT,wp,dst,red); break;
    case 29: run_slot< 3,0,3,3,true ,4,3,PART>(tile,xT,wp,dst,red); break;
    case 30: run_slot<17,3,0,3,false,4,3,PART>(tile,xT,wp,dst,red); break;
    case 31: run_slot< 1,0,1,1,true ,0,3,PART>(tile,xT,wp,dst,red); break;
    case 32: run_slot< 4,1,0,1,false,0,3,PART>(tile,xT,wp,dst,red); break;
    case 33: run_slot<13,2,2,0,false,0,1,PART>(tile,xT,wp,dst,red); break;
    case 34: run_slot< 5,1,1,0,false,0,1,PART>(tile,xT,wp,dst,red); break;
    case 35: run_slot< 0,0,0,0,false,0,1,PART>(tile,xT,wp,dst,red); break;
    default: break;
  }
}

// ---------------------------------------------------------------------------
// Gather: out[z][seg] = sum of per-path partials (coeff already folded in)
// ---------------------------------------------------------------------------
__global__ void gather_out(const float* __restrict__ part, float* __restrict__ out){
  int gid = blockIdx.x * 256 + threadIdx.x;
  int z = gid >> 10, j = gid & 1023;
  float s;
  if (j < 64){                               // l3=0: paths {0,5,13,21}
    size_t b = (size_t)z*64 + j;
    s = part[(size_t)K3CUM[0]*ZW + b] + part[(size_t)K3CUM[5]*ZW + b]
      + part[(size_t)K3CUM[13]*ZW + b] + part[(size_t)K3CUM[21]*ZW + b];
  } else if (j < 256){                       // l3=1: paths {1,4,7,11,15,19}
    size_t b = (size_t)z*192 + (j - 64);
    s = part[(size_t)K3CUM[1]*ZW + b] + part[(size_t)K3CUM[4]*ZW + b]
      + part[(size_t)K3CUM[7]*ZW + b] + part[(size_t)K3CUM[11]*ZW + b]
      + part[(size_t)K3CUM[15]*ZW + b] + part[(size_t)K3CUM[19]*ZW + b];
  } else if (j < 576){                       // l3=2: paths {2,6,9,10,14,18,22}
    size_t b = (size_t)z*320 + (j - 256);
    s = part[(size_t)K3CUM[2]*ZW + b] + part[(size_t)K3CUM[6]*ZW + b]
      + part[(size_t)K3CUM[9]*ZW + b] + part[(size_t)K3CUM[10]*ZW + b]
      + part[(size_t)K3CUM[14]*ZW + b] + part[(size_t)K3CUM[18]*ZW + b]
      + part[(size_t)K3CUM[22]*ZW + b];
  } else {                                   // l3=3: paths {3,8,12,16,17,20}
    size_t b = (size_t)z*448 + (j - 576);
    s = part[(size_t)K3CUM[3]*ZW + b] + part[(size_t)K3CUM[8]*ZW + b]
      + part[(size_t)K3CUM[12]*ZW + b] + part[(size_t)K3CUM[16]*ZW + b]
      + part[(size_t)K3CUM[17]*ZW + b] + part[(size_t)K3CUM[20]*ZW + b];
  }
  out[gid] = s;
}

// ---------------------------------------------------------------------------
extern "C" void kernel_launch(void* const* d_in, const int* in_sizes, int n_in,
                              void* d_out, int out_size, void* d_ws, size_t ws_size,
                              hipStream_t stream)
{
  const float* x = (const float*)d_in[0];        // [2,1024,1024] fp32
  const float* w = (const float*)d_in[1];        // [23,64,64,64] fp32
  float* out = (float*)d_out;                    // [2,1024,1024] fp32

  const size_t packB = 23ull*64*2*4*64*8 * sizeof(unsigned short);   // 12,058,624
  const size_t xTB   = 1024ull*2048*sizeof(float);                   //  8,388,608
  const size_t partB = 99ull*ZW*sizeof(float);                       // 51,904,512
  const int totalW = 23*64*2*4*64*8;

  unsigned short* wp = (unsigned short*)d_ws;
  float* xT   = (float*)((char*)d_ws + packB);
  float* part = (float*)((char*)d_ws + packB + xTB);

  if (ws_size < packB + xTB) return;

  pack_w_kernel<<<(totalW + 255)/256, 256, 0, stream>>>(w, wp, totalW);
  dim3 tg(32, 64);
  transpose_x<<<tg, 256, 0, stream>>>(x, xT);

  if (ws_size >= packB + xTB + partB){
    tp_main<true><<<36*128, 128, 0, stream>>>(xT, wp, part);
    gather_out<<<(2048*1024)/256, 256, 0, stream>>>(part, out);
  } else {
    hipMemsetAsync(d_out, 0, (size_t)out_size * sizeof(float), stream);
    tp_main<false><<<36*128, 128, 0, stream>>>(xT, wp, out);
  }
}